// Round 2
// baseline (1010.740 us; speedup 1.0000x reference)
//
#include <hip/hip_runtime.h>

#define D 256
#define KCODES 8192
#define NTOK 16384            // 16 * 1024
#define BM 64                 // tokens per block tile
#define BN 128                // codes per tile iteration
#define KCH 16                // k-chunk staged in LDS
#define NSPLIT 4              // code-range splits (grid.y) for occupancy
#define SPLITC (KCODES / NSPLIT)
#define XS_LD 260             // 64x260 fp32: rows 1040B (16B aligned), banks 2-way max
#define ES_LD 132             // 16x132 fp32: rows 528B (16B aligned)
#define QSIZE (NTOK * D)
#define SMEM_BYTES ((BM * XS_LD + KCH * ES_LD) * 4)   // 75008 B -> 2 blocks/CU

// ---- K1a: e2[c] = sum(codebook[c,:]^2), one wave per code ----
__global__ __launch_bounds__(256) void e2_kernel(const float* __restrict__ cb,
                                                 float* __restrict__ e2) {
    int c = blockIdx.x * 4 + (threadIdx.x >> 6);
    int lane = threadIdx.x & 63;
    float4 v = reinterpret_cast<const float4*>(cb + (size_t)c * D)[lane];
    float s = v.x * v.x + v.y * v.y + v.z * v.z + v.w * v.w;
#pragma unroll
    for (int off = 32; off > 0; off >>= 1) s += __shfl_down(s, off);
    if (lane == 0) e2[c] = s;
}

// ---- K1b: xsq[t] = sum(x[t,:]^2), one wave per token ----
__global__ __launch_bounds__(256) void xsq_kernel(const float* __restrict__ x,
                                                  float* __restrict__ xsq) {
    int t = blockIdx.x * 4 + (threadIdx.x >> 6);
    int lane = threadIdx.x & 63;
    float4 v = reinterpret_cast<const float4*>(x + (size_t)t * D)[lane];
    float s = v.x * v.x + v.y * v.y + v.z * v.z + v.w * v.w;
#pragma unroll
    for (int off = 32; off > 0; off >>= 1) s += __shfl_down(s, off);
    if (lane == 0) xsq[t] = s;
}

// ---- K2: per-token argmin of fp32 d = (xsq + e2) - 2*dot over a code split ----
// dot = single sequential fma chain over k ascending (matches BLAS microkernel),
// d quantized at ulp(~256) exactly like the numpy reference -> ties are real;
// tie-break everywhere to SMALLEST code index (np.argmin semantics).
// block: 256 threads as 16(tx: codes) x 16(ty: tokens); thread tile 4 tokens x 8 codes
__global__ __launch_bounds__(256, 2) void argmin_kernel(
    const float* __restrict__ x, const float* __restrict__ cb,
    const float* __restrict__ e2, const float* __restrict__ xsq,
    float* __restrict__ bestVal, int* __restrict__ bestIdx) {
    extern __shared__ float smem[];
    float* xs = smem;                // [BM][XS_LD]
    float* es = smem + BM * XS_LD;   // [KCH][ES_LD]

    const int tid = threadIdx.x;
    const int tx = tid & 15;
    const int ty = tid >> 4;
    const int t0 = blockIdx.x * BM;
    const int split = blockIdx.y;

    // stage x tile: coalesced 1KB-per-wave reads, b128 LDS writes (2-way banks)
#pragma unroll
    for (int r = 0; r < 16; ++r) {
        int idx = r * 256 + tid;
        int t = idx >> 6;
        int k4 = idx & 63;
        float4 v = reinterpret_cast<const float4*>(x + (size_t)(t0 + t) * D)[k4];
        *reinterpret_cast<float4*>(xs + t * XS_LD + k4 * 4) = v;
    }

    float xq[4];
#pragma unroll
    for (int m = 0; m < 4; ++m) xq[m] = xsq[t0 + ty * 4 + m];

    float runBest[4];
    int runIdx[4];
#pragma unroll
    for (int m = 0; m < 4; ++m) { runBest[m] = 3.4e38f; runIdx[m] = 0; }

    const int cstart = split * SPLITC;
    for (int ct = 0; ct < SPLITC / BN; ++ct) {
        const int cbase = cstart + ct * BN;
        float acc[4][8];
#pragma unroll
        for (int m = 0; m < 4; ++m)
#pragma unroll
            for (int n = 0; n < 8; ++n) acc[m][n] = 0.f;

        float4 pre[2];
#pragma unroll
        for (int j = 0; j < 2; ++j) {
            int f = j * 256 + tid;
            int c = f >> 2, slot = f & 3;
            pre[j] = reinterpret_cast<const float4*>(cb + (size_t)(cbase + c) * D)[slot];
        }

        for (int kk = 0; kk < D; kk += KCH) {
            __syncthreads();   // previous-chunk readers done
#pragma unroll
            for (int j = 0; j < 2; ++j) {
                int f = j * 256 + tid;
                int c = f >> 2, slot = f & 3;
                es[(slot * 4 + 0) * ES_LD + c] = pre[j].x;
                es[(slot * 4 + 1) * ES_LD + c] = pre[j].y;
                es[(slot * 4 + 2) * ES_LD + c] = pre[j].z;
                es[(slot * 4 + 3) * ES_LD + c] = pre[j].w;
            }
            __syncthreads();
            if (kk + KCH < D) {   // prefetch next chunk into registers (overlaps compute)
#pragma unroll
                for (int j = 0; j < 2; ++j) {
                    int f = j * 256 + tid;
                    int c = f >> 2, slot = f & 3;
                    pre[j] = reinterpret_cast<const float4*>(
                        cb + (size_t)(cbase + c) * D + kk + KCH)[slot];
                }
            }
            // k ascending, ONE fma chain per (token, code) — order matters for
            // bit-compat with the numpy/BLAS reference accumulation.
#pragma unroll
            for (int k = 0; k < KCH; ++k) {
                float xv[4];
#pragma unroll
                for (int m = 0; m < 4; ++m)
                    xv[m] = xs[(ty * 4 + m) * XS_LD + kk + k];
                float4 e0 = *reinterpret_cast<const float4*>(es + k * ES_LD + tx * 4);
                float4 e1 = *reinterpret_cast<const float4*>(es + k * ES_LD + 64 + tx * 4);
                float ev[8] = {e0.x, e0.y, e0.z, e0.w, e1.x, e1.y, e1.z, e1.w};
#pragma unroll
                for (int m = 0; m < 4; ++m)
#pragma unroll
                    for (int n = 0; n < 8; ++n)
                        acc[m][n] = fmaf(xv[m], ev[n], acc[m][n]);
            }
        }

        // numpy-identical distance: d = fl( fl(xsq + e2) - 2*dot )
        float e2v[8];
#pragma unroll
        for (int n = 0; n < 4; ++n) {
            e2v[n] = e2[cbase + tx * 4 + n];
            e2v[n + 4] = e2[cbase + 64 + tx * 4 + n];
        }
#pragma unroll
        for (int m = 0; m < 4; ++m) {
#pragma unroll
            for (int n = 0; n < 8; ++n) {
                int c = cbase + (n < 4 ? tx * 4 + n : 64 + tx * 4 + (n - 4));
                float t = xq[m] + e2v[n];
                float dd = fmaf(-2.0f, acc[m][n], t);   // == fl(t - 2*dot), 2*dot exact
                // ascending c + strict '<' keeps the FIRST (lowest-index) min on ties
                if (dd < runBest[m]) { runBest[m] = dd; runIdx[m] = c; }
            }
        }
    }

    // cross-tx butterfly (lanes differ in bits 0..3); equal d -> smaller idx
#pragma unroll
    for (int m = 0; m < 4; ++m) {
        float b = runBest[m];
        int bi = runIdx[m];
#pragma unroll
        for (int off = 1; off < 16; off <<= 1) {
            float ob = __shfl_xor(b, off);
            int oi = __shfl_xor(bi, off);
            if (ob < b || (ob == b && oi < bi)) { b = ob; bi = oi; }
        }
        if (tx == 0) {
            int token = t0 + ty * 4 + m;
            bestVal[(size_t)split * NTOK + token] = b;
            bestIdx[(size_t)split * NTOK + token] = bi;
        }
    }
}

// ---- K3: combine splits, gather codebook row, emit quantized + idx + partial loss ----
__global__ __launch_bounds__(256) void gather_kernel(
    const float* __restrict__ x, const float* __restrict__ cb,
    const float* __restrict__ bestVal, const int* __restrict__ bestIdx,
    float* __restrict__ out, float* __restrict__ partial) {
    __shared__ int sIdx;
    __shared__ float red[4];
    const int token = blockIdx.x;
    const int tid = threadIdx.x;
    if (tid == 0) {
        float b = bestVal[token];
        int bi = bestIdx[token];
#pragma unroll
        for (int s = 1; s < NSPLIT; ++s) {
            float ob = bestVal[(size_t)s * NTOK + token];
            int oi = bestIdx[(size_t)s * NTOK + token];
            if (ob < b || (ob == b && oi < bi)) { b = ob; bi = oi; }
        }
        sIdx = bi;
    }
    __syncthreads();
    const int idx = sIdx;
    float q = cb[(size_t)idx * D + tid];
    float xv = x[(size_t)token * D + tid];
    out[(size_t)token * D + tid] = q;
    float d = q - xv;
    d = d * d;
#pragma unroll
    for (int off = 32; off > 0; off >>= 1) d += __shfl_down(d, off);
    if ((tid & 63) == 0) red[tid >> 6] = d;
    __syncthreads();
    if (tid == 0) {
        partial[token] = red[0] + red[1] + red[2] + red[3];
        out[(size_t)QSIZE + token] = (float)idx;   // index emitted as fp32 value
    }
}

// ---- K4: final loss reduction ----
__global__ __launch_bounds__(256) void loss_kernel(const float* __restrict__ partial,
                                                   float* __restrict__ out) {
    __shared__ float red[4];
    float s = 0.f;
    for (int i = threadIdx.x; i < NTOK; i += 256) s += partial[i];
#pragma unroll
    for (int off = 32; off > 0; off >>= 1) s += __shfl_down(s, off);
    if ((threadIdx.x & 63) == 0) red[threadIdx.x >> 6] = s;
    __syncthreads();
    if (threadIdx.x == 0) {
        float total = red[0] + red[1] + red[2] + red[3];
        out[(size_t)QSIZE + NTOK] = 0.25f * total / (float)QSIZE;
    }
}

extern "C" void kernel_launch(void* const* d_in, const int* in_sizes, int n_in,
                              void* d_out, int out_size, void* d_ws, size_t ws_size,
                              hipStream_t stream) {
    const float* x = (const float*)d_in[0];     // [16384, 256]
    const float* cb = (const float*)d_in[1];    // [8192, 256]
    float* out = (float*)d_out;
    float* ws = (float*)d_ws;

    // workspace (floats): e2[8192] | xsq[16384] | bestVal[4*16384] | bestIdx[4*16384] | partial[16384]
    float* e2 = ws;
    float* xsq = ws + KCODES;
    float* bestVal = ws + KCODES + NTOK;
    int* bestIdx = (int*)(ws + KCODES + NTOK + NSPLIT * NTOK);
    float* partial = ws + KCODES + NTOK + 2 * NSPLIT * NTOK;

    // 75008 B dynamic LDS > 64 KB default cap
    hipFuncSetAttribute((const void*)argmin_kernel,
                        hipFuncAttributeMaxDynamicSharedMemorySize, SMEM_BYTES);

    e2_kernel<<<KCODES / 4, 256, 0, stream>>>(cb, e2);
    xsq_kernel<<<NTOK / 4, 256, 0, stream>>>(x, xsq);
    argmin_kernel<<<dim3(NTOK / BM, NSPLIT), 256, SMEM_BYTES, stream>>>(
        x, cb, e2, xsq, bestVal, bestIdx);
    gather_kernel<<<NTOK, 256, 0, stream>>>(x, cb, bestVal, bestIdx, out, partial);
    loss_kernel<<<1, 256, 0, stream>>>(partial, out);
}